// Round 5
// baseline (168.670 us; speedup 1.0000x reference)
//
#include <hip/hip_runtime.h>
#include <cstdint>
#include <cstddef>

#define KCAT  384
#define AST   392            // padded LDS A-row stride (elems); multiple of 8 for uint4 rows
#define NPB   16             // nodes per fused block
#define PREPV 128            // prep blocks doing V

typedef __attribute__((ext_vector_type(8))) short bf16x8;
typedef __attribute__((ext_vector_type(4))) float f32x4;

// f32 -> bf16 (round to nearest even), bit-level (inputs are finite)
static __device__ __forceinline__ unsigned short f2bf(float f) {
    unsigned int u = __builtin_bit_cast(unsigned int, f);
    unsigned int lsb = (u >> 16) & 1u;
    u += 0x7fffu + lsb;
    return (unsigned short)(u >> 16);
}
static __device__ __forceinline__ float bfhi(unsigned int u) {
    return __builtin_bit_cast(float, u & 0xFFFF0000u);
}
static __device__ __forceinline__ float bflo(unsigned int u) {
    return __builtin_bit_cast(float, u << 16);
}
static __device__ __forceinline__ void acc8(float* a, const uint4& v) {
    a[0] += bflo(v.x); a[1] += bfhi(v.x); a[2] += bflo(v.y); a[3] += bfhi(v.y);
    a[4] += bflo(v.z); a[5] += bfhi(v.z); a[6] += bflo(v.w); a[7] += bfhi(v.w);
}

// ---------------- Prep: V (bf16 concat), xb = bf16(x), blkoff = lower_bound(dst, b*NPB) ----------------
__global__ __launch_bounds__(256)
void prep(const float* __restrict__ x, const float* __restrict__ Wg,
          const float* __restrict__ Wl, const float* __restrict__ Ws,
          const int* __restrict__ dst, unsigned short* __restrict__ V,
          unsigned short* __restrict__ xb, int* __restrict__ blkoff,
          int total8, int nblk, int noffb, int E) {
    const int bx = blockIdx.x;
    const int t  = threadIdx.x;
    if (bx < PREPV) {
        // V row bx: k = t (0..255) and 256+t (t<128)
        const int o = bx;
        float v = (t < 128) ? Wg[o * 128 + t] : Wl[o * 128 + (t - 128)];
        V[o * KCAT + t] = f2bf(v);
        if (t < 128) V[o * KCAT + 256 + t] = f2bf(Ws[o * 128 + t]);
    } else if (bx < PREPV + noffb) {
        // per-fused-block edge offset via binary search on sorted dst
        int b = (bx - PREPV) * 256 + t;
        if (b < nblk) {
            int target = b * NPB;
            int lo = 0, hi = E;
            while (lo < hi) { int mid = (lo + hi) >> 1; if (dst[mid] < target) lo = mid + 1; else hi = mid; }
            blkoff[b] = lo;
        }
    } else {
        // xb: one thread per 8 elems (32B in, 16B out)
        int gid = (bx - PREPV - noffb) * 256 + t;
        if (gid < total8) {
            const float4* px = (const float4*)x + (size_t)gid * 2;
            float4 a = px[0], bq = px[1];
            uint4 u;
            u.x = (unsigned)f2bf(a.x)  | ((unsigned)f2bf(a.y)  << 16);
            u.y = (unsigned)f2bf(a.z)  | ((unsigned)f2bf(a.w)  << 16);
            u.z = (unsigned)f2bf(bq.x) | ((unsigned)f2bf(bq.y) << 16);
            u.w = (unsigned)f2bf(bq.z) | ((unsigned)f2bf(bq.w) << 16);
            ((uint4*)xb)[gid] = u;
        }
    }
}

// ---------------- Fused: gather-mean -> LDS A-panel (16 x 392) -> MFMA -> ELU ----------------
// 256 threads = 4 waves, 16 nodes/block, 3125 blocks, 12.5 KB LDS -> 8 blocks/CU target.
// Phase 1: wave wv gathers nodes wv*4..wv*4+3; all 4 idx vectors prefetched (independent
// coalesced loads); deg<=32 -> edge loop fully unrolled (one 16-edge group + guarded 2nd).
// Phase 2: A-frags broadcast from LDS (all waves share the 16 rows); each wave owns 32 cols;
// B direct from L2-resident V with register prefetch; no barriers in K-loop.
__global__ __launch_bounds__(256, 8)
void fused_agg_gemm(const unsigned short* __restrict__ xb, const int* __restrict__ src,
                    const int* __restrict__ deg, const int* __restrict__ blkoff,
                    const unsigned short* __restrict__ V, const float* __restrict__ bias,
                    float* __restrict__ out, int N) {
    __shared__ __align__(16) unsigned short Ash[NPB * AST];   // 12544 B
    __shared__ int sstart[NPB];
    __shared__ int sdeg[NPB];
    const int t    = threadIdx.x;
    const int wv   = t >> 6;             // 0..3
    const int lane = t & 63;
    const int c    = lane & 15;          // 16B column within 256B bf16 row
    const int p    = lane >> 4;          // parity 0..3
    const int base = blockIdx.x * NPB;

    if (wv == 0) {
        int lo = blkoff[blockIdx.x];     // broadcast load
        int n  = base + lane;
        int dg = (lane < NPB && n < N) ? deg[n] : 0;
        int incl = dg;
#pragma unroll
        for (int off = 1; off < NPB; off <<= 1) {
            int v = __shfl_up(incl, off, 64);
            if (lane >= off) incl += v;
        }
        if (lane < NPB) { sstart[lane] = lo + incl - dg; sdeg[lane] = dg; }
    }
    __syncthreads();

    // ---- Phase 1: gather (4 nodes per wave, idx prefetched for all 4)
    const uint4* x4 = (const uint4*)xb;
    int dgs[4], sss[4], idxs[4];
#pragma unroll
    for (int r = 0; r < 4; ++r) {
        int row = wv * 4 + r;
        dgs[r] = sdeg[row];
        sss[r] = sstart[row];
        idxs[r] = 0;
        if (lane < dgs[r]) idxs[r] = src[sss[r] + lane];   // coalesced, d <= 32
    }
#pragma unroll
    for (int r = 0; r < 4; ++r) {
        const int row = wv * 4 + r;
        const int n   = base + row;
        const int d   = dgs[r];
        uint4 xv = {0, 0, 0, 0};
        if (p == 1 && n < N) xv = x4[(size_t)n * 16 + c];

        float a[8] = {0,0,0,0,0,0,0,0};
        float b[8] = {0,0,0,0,0,0,0,0};
        {   // edges 0..15: this parity covers p, p+4, p+8, p+12
            int r0 = __shfl(idxs[r], p, 64);
            int r1 = __shfl(idxs[r], p + 4, 64);
            int r2 = __shfl(idxs[r], p + 8, 64);
            int r3 = __shfl(idxs[r], p + 12, 64);
            uint4 v0 = x4[(size_t)r0 * 16 + c];
            uint4 v1 = x4[(size_t)r1 * 16 + c];
            uint4 v2 = x4[(size_t)r2 * 16 + c];
            uint4 v3 = x4[(size_t)r3 * 16 + c];
            if (p < d)      acc8(a, v0);
            if (p + 4 < d)  acc8(b, v1);
            if (p + 8 < d)  acc8(a, v2);
            if (p + 12 < d) acc8(b, v3);
        }
        if (d > 16) {   // edges 16..31
            int e0 = 16 + p;
            int r0 = __shfl(idxs[r], e0, 64);
            int r1 = __shfl(idxs[r], e0 + 4, 64);
            int r2 = __shfl(idxs[r], e0 + 8, 64);
            int r3 = __shfl(idxs[r], e0 + 12, 64);
            uint4 v0 = x4[(size_t)r0 * 16 + c];
            uint4 v1 = x4[(size_t)r1 * 16 + c];
            uint4 v2 = x4[(size_t)r2 * 16 + c];
            uint4 v3 = x4[(size_t)r3 * 16 + c];
            if (e0 < d)      acc8(a, v0);
            if (e0 + 4 < d)  acc8(b, v1);
            if (e0 + 8 < d)  acc8(a, v2);
            if (e0 + 12 < d) acc8(b, v3);
        }
#pragma unroll
        for (int i = 0; i < 8; ++i) a[i] += b[i];
#pragma unroll
        for (int i = 0; i < 8; ++i) {
            a[i] += __shfl_xor(a[i], 16, 64);
            a[i] += __shfl_xor(a[i], 32, 64);
        }
        unsigned short* arow = Ash + row * AST;
        if (p == 0) {
            float inv = (d > 0) ? 1.0f / (float)d : 0.0f;
            uint4 u;
            u.x = (unsigned)f2bf(a[0]*inv) | ((unsigned)f2bf(a[1]*inv) << 16);
            u.y = (unsigned)f2bf(a[2]*inv) | ((unsigned)f2bf(a[3]*inv) << 16);
            u.z = (unsigned)f2bf(a[4]*inv) | ((unsigned)f2bf(a[5]*inv) << 16);
            u.w = (unsigned)f2bf(a[6]*inv) | ((unsigned)f2bf(a[7]*inv) << 16);
            *(uint4*)(arow + 128 + c * 8) = u;
        } else if (p == 1) {
            *(uint4*)(arow + c * 8) = xv;
            uint4 z = xv;
            if (d == 0) { z.x = 0; z.y = 0; z.z = 0; z.w = 0; }
            *(uint4*)(arow + 256 + c * 8) = z;
        }
    }
    __syncthreads();

    // ---- Phase 2: 16x128 GEMM; wave wv owns cols wv*32..wv*32+31 (1x2 MFMAs, 12 k-steps)
    const int quad = lane >> 4;
    const int wcol = wv * 32;
    const unsigned short* V0 = V + (size_t)(wcol + c) * KCAT + quad * 8;
    const unsigned short* V1 = V + (size_t)(wcol + 16 + c) * KCAT + quad * 8;

    f32x4 acc0 = (f32x4){0.f, 0.f, 0.f, 0.f};
    f32x4 acc1 = (f32x4){0.f, 0.f, 0.f, 0.f};
    bf16x8 b0 = *(const bf16x8*)V0;
    bf16x8 b1 = *(const bf16x8*)V1;
    for (int k0 = 0; k0 < KCAT; k0 += 32) {
        int kn = (k0 + 32 < KCAT) ? k0 + 32 : 0;   // branchless prefetch (last redundant)
        bf16x8 n0 = *(const bf16x8*)(V0 + kn);
        bf16x8 n1 = *(const bf16x8*)(V1 + kn);
        bf16x8 a0 = *(const bf16x8*)(Ash + (size_t)c * AST + k0 + quad * 8);
        acc0 = __builtin_amdgcn_mfma_f32_16x16x32_bf16(a0, b0, acc0, 0, 0, 0);
        acc1 = __builtin_amdgcn_mfma_f32_16x16x32_bf16(a0, b1, acc1, 0, 0, 0);
        b0 = n0; b1 = n1;
    }

    // epilogue: + bias, ELU, store f32. C/D: col=lane&15, row=quad*4+reg
    const int col0 = wcol + c, col1 = wcol + 16 + c;
    const float bv0 = bias[col0], bv1 = bias[col1];
#pragma unroll
    for (int reg = 0; reg < 4; ++reg) {
        int grow = base + quad * 4 + reg;
        if (grow < N) {
            float v0 = acc0[reg] + bv0;
            float v1 = acc1[reg] + bv1;
            out[(size_t)grow * 128 + col0] = (v0 > 0.f) ? v0 : expm1f(v0);
            out[(size_t)grow * 128 + col1] = (v1 > 0.f) ? v1 : expm1f(v1);
        }
    }
}

extern "C" void kernel_launch(void* const* d_in, const int* in_sizes, int n_in,
                              void* d_out, int out_size, void* d_ws, size_t ws_size,
                              hipStream_t stream) {
    const float* x  = (const float*)d_in[0];
    const float* Wg = (const float*)d_in[1];
    const float* Wl = (const float*)d_in[2];
    const float* Ws = (const float*)d_in[3];
    const float* b  = (const float*)d_in[4];
    const int*   src = (const int*)d_in[5];
    const int*   dst = (const int*)d_in[6];
    const int*   deg = (const int*)d_in[7];
    const int E = in_sizes[5];
    const int N = in_sizes[7];
    float* out = (float*)d_out;

    unsigned short* V      = (unsigned short*)d_ws;                        // 98304 B
    int*            blkoff = (int*)((char*)d_ws + 98304);                  // 16 KB
    unsigned short* xb     = (unsigned short*)((char*)d_ws + 98304 + 16384);

    const int nblk   = (N + NPB - 1) / NPB;        // 3125
    const int noffb  = (nblk + 255) / 256;         // 13
    const int total8 = N * 16;
    const int nconv  = (total8 + 255) / 256;       // 3125

    prep<<<dim3(PREPV + noffb + nconv), dim3(256), 0, stream>>>(
        x, Wg, Wl, Ws, dst, V, xb, blkoff, total8, nblk, noffb, E);
    fused_agg_gemm<<<dim3(nblk), dim3(256), 0, stream>>>(
        xb, src, deg, blkoff, V, b, out, N);
}

// Round 6
// 141.418 us; speedup vs baseline: 1.1927x; 1.1927x over previous
//
#include <hip/hip_runtime.h>
#include <cstdint>
#include <cstddef>

#define KCAT 384
#define GNPB 8        // nodes per gather block (8 waves, 1 node/wave)
#define MNPB 16       // rows per gemm block
#define GAST 264      // gemm LDS A row stride in elems (528 B) — breaks 512B-stride banks
#define VP_BLOCKS 24  // prep blocks packing Vp (6144 threads)

typedef __attribute__((ext_vector_type(8))) short bf16x8;
typedef __attribute__((ext_vector_type(4))) float f32x4;

static __device__ __forceinline__ unsigned short f2bf(float f) {
    unsigned int u = __builtin_bit_cast(unsigned int, f);
    u += 0x7fffu + ((u >> 16) & 1u);
    return (unsigned short)(u >> 16);
}
static __device__ __forceinline__ float bfhi(unsigned int u) { return __builtin_bit_cast(float, u & 0xFFFF0000u); }
static __device__ __forceinline__ float bflo(unsigned int u) { return __builtin_bit_cast(float, u << 16); }
// masked bf16x8 accumulate: m = all-ones keeps, 0 zeroes (bf16 0x0000 == +0.0)
static __device__ __forceinline__ void acc8(float* a, const uint4& v, unsigned m) {
    unsigned x0 = v.x & m, x1 = v.y & m, x2 = v.z & m, x3 = v.w & m;
    a[0] += bflo(x0); a[1] += bfhi(x0); a[2] += bflo(x1); a[3] += bfhi(x1);
    a[4] += bflo(x2); a[5] += bfhi(x2); a[6] += bflo(x3); a[7] += bfhi(x3);
}

// ---------------- Prep: Vp pack (GEMM B layout), xb = bf16(x), blkoff ----------------
// Vp layout: element ((g*12 + s)*64 + lane)*8 + j  =  W[g*16 + (lane&15)][s*32 + (lane>>4)*8 + j]
// so a wave's B-fragment load for (col-group g, kstep s) is ONE contiguous 1KB read.
__global__ __launch_bounds__(256)
void prep(const float* __restrict__ x, const float* __restrict__ Wg,
          const float* __restrict__ Wl, const float* __restrict__ Ws,
          const int* __restrict__ dst, unsigned short* __restrict__ Vp,
          unsigned short* __restrict__ xb, int* __restrict__ blkoff,
          int total8, int nblk_g, int noffb, int E) {
    const int bx = blockIdx.x, t = threadIdx.x;
    if (bx < VP_BLOCKS) {
        int gid = bx * 256 + t;
        if (gid < 6144) {
            int l = gid & 63, srow = (gid >> 6) % 12, g = gid / 768;
            int o = g * 16 + (l & 15);
            int k = srow * 32 + (l >> 4) * 8;
            const float* w; int kk;
            if (k < 128)      { w = Wg; kk = k; }
            else if (k < 256) { w = Wl; kk = k - 128; }
            else              { w = Ws; kk = k - 256; }
            const float* p = w + o * 128 + kk;
            uint4 u;
            u.x = (unsigned)f2bf(p[0]) | ((unsigned)f2bf(p[1]) << 16);
            u.y = (unsigned)f2bf(p[2]) | ((unsigned)f2bf(p[3]) << 16);
            u.z = (unsigned)f2bf(p[4]) | ((unsigned)f2bf(p[5]) << 16);
            u.w = (unsigned)f2bf(p[6]) | ((unsigned)f2bf(p[7]) << 16);
            ((uint4*)Vp)[gid] = u;
        }
    } else if (bx < VP_BLOCKS + noffb) {
        int b = (bx - VP_BLOCKS) * 256 + t;
        if (b < nblk_g) {
            int target = b * GNPB;
            int lo = 0, hi = E;
            while (lo < hi) { int mid = (lo + hi) >> 1; if (dst[mid] < target) lo = mid + 1; else hi = mid; }
            blkoff[b] = lo;
        }
    } else {
        int gid = (bx - VP_BLOCKS - noffb) * 256 + t;
        if (gid < total8) {
            const float4* px = (const float4*)x + (size_t)gid * 2;
            float4 a = px[0], bq = px[1];
            uint4 u;
            u.x = (unsigned)f2bf(a.x)  | ((unsigned)f2bf(a.y)  << 16);
            u.y = (unsigned)f2bf(a.z)  | ((unsigned)f2bf(a.w)  << 16);
            u.z = (unsigned)f2bf(bq.x) | ((unsigned)f2bf(bq.y) << 16);
            u.w = (unsigned)f2bf(bq.z) | ((unsigned)f2bf(bq.w) << 16);
            ((uint4*)xb)[gid] = u;
        }
    }
}

// ---------------- Gather: M[n] = (deg>0) ? mean_e xb[src[e]] : 0  (bf16) ----------------
// One node per wave, 8 waves/block, barrier-free. lane = parity(p=lane>>4) x 16B-col(c).
// All row-loads (up to 8) issued before any accumulate -> 8 in flight per wave.
__global__ __launch_bounds__(512, 7)
void gather(const unsigned short* __restrict__ xb, const int* __restrict__ src,
            const int* __restrict__ deg, const int* __restrict__ blkoff,
            unsigned short* __restrict__ M, int N) {
    const int t = threadIdx.x, wv = t >> 6, lane = t & 63;
    const int c = lane & 15, p = lane >> 4;
    const int base = blockIdx.x * GNPB;

    // every wave redundantly scans the block's 8 degs (broadcast loads, no LDS/barrier)
    int dg8 = 0;
    if (lane < GNPB && base + lane < N) dg8 = deg[base + lane];
    int incl = dg8;
#pragma unroll
    for (int off = 1; off < GNPB; off <<= 1) {
        int v = __shfl_up(incl, off, 64);
        if (lane >= off) incl += v;
    }
    const int d = __shfl(dg8, wv, 64);
    const int s = blkoff[blockIdx.x] + __shfl(incl, wv, 64) - d;
    const int n = base + wv;
    if (n >= N) return;

    int idx = 0;
    if (lane < d) idx = src[s + lane];      // one coalesced shot, d <= 32

    const uint4* x4 = (const uint4*)xb;
    int r0 = __shfl(idx, p, 64),      r1 = __shfl(idx, p + 4, 64);
    int r2 = __shfl(idx, p + 8, 64),  r3 = __shfl(idx, p + 12, 64);
    uint4 v0 = x4[(size_t)r0 * 16 + c], v1 = x4[(size_t)r1 * 16 + c];
    uint4 v2 = x4[(size_t)r2 * 16 + c], v3 = x4[(size_t)r3 * 16 + c];
    uint4 v4, v5, v6, v7;
    const bool two = (d > 16);
    if (two) {                               // issue second batch BEFORE accumulating first
        int e = 16 + p;
        int r4 = __shfl(idx, e, 64),      r5 = __shfl(idx, e + 4, 64);
        int r6 = __shfl(idx, e + 8, 64),  r7 = __shfl(idx, e + 12, 64);
        v4 = x4[(size_t)r4 * 16 + c]; v5 = x4[(size_t)r5 * 16 + c];
        v6 = x4[(size_t)r6 * 16 + c]; v7 = x4[(size_t)r7 * 16 + c];
    }
    float a[8] = {0,0,0,0,0,0,0,0};
    float b[8] = {0,0,0,0,0,0,0,0};
    acc8(a, v0, (p      < d) ? ~0u : 0u);
    acc8(b, v1, (p + 4  < d) ? ~0u : 0u);
    acc8(a, v2, (p + 8  < d) ? ~0u : 0u);
    acc8(b, v3, (p + 12 < d) ? ~0u : 0u);
    if (two) {
        int e = 16 + p;
        acc8(a, v4, (e      < d) ? ~0u : 0u);
        acc8(b, v5, (e + 4  < d) ? ~0u : 0u);
        acc8(a, v6, (e + 8  < d) ? ~0u : 0u);
        acc8(b, v7, (e + 12 < d) ? ~0u : 0u);
    }
#pragma unroll
    for (int i = 0; i < 8; ++i) a[i] += b[i];
#pragma unroll
    for (int i = 0; i < 8; ++i) {
        a[i] += __shfl_xor(a[i], 16, 64);
        a[i] += __shfl_xor(a[i], 32, 64);
    }
    if (p == 0) {
        float inv = (d > 0) ? 1.0f / (float)d : 0.0f;
        uint4 u;
        u.x = (unsigned)f2bf(a[0]*inv) | ((unsigned)f2bf(a[1]*inv) << 16);
        u.y = (unsigned)f2bf(a[2]*inv) | ((unsigned)f2bf(a[3]*inv) << 16);
        u.z = (unsigned)f2bf(a[4]*inv) | ((unsigned)f2bf(a[5]*inv) << 16);
        u.w = (unsigned)f2bf(a[6]*inv) | ((unsigned)f2bf(a[7]*inv) << 16);
        ((uint4*)M)[(size_t)n * 16 + c] = u;
    }
}

// ---------------- GEMM: out = elu([xb | M | mask.xb] @ V^T + b) ----------------
// 16 rows/block, 3125 blocks, 256 threads. A-panel (xb row + M row, 512B -> padded 528B)
// staged ONCE -> single barrier. Third K-segment reuses the xb LDS data with a per-row
// deg mask ANDed into the A-fragment. B streamed from packed Vp (contiguous 1KB wave
// reads, L2-resident) with register prefetch; no barriers in the K-loop.
__global__ __launch_bounds__(256)
void gemm(const unsigned short* __restrict__ xb, const unsigned short* __restrict__ Mm,
          const int* __restrict__ deg, const unsigned short* __restrict__ Vp,
          const float* __restrict__ bias, float* __restrict__ out, int N) {
    __shared__ __align__(16) unsigned short As[MNPB * GAST];
    __shared__ unsigned smask[MNPB];
    const int t = threadIdx.x, wv = t >> 6, lane = t & 63;
    const int c = lane & 15, quad = lane >> 4;
    const int base = blockIdx.x * MNPB;

    if (t < MNPB) smask[t] = (base + t < N && deg[base + t] > 0) ? 0xFFFFFFFFu : 0u;
#pragma unroll
    for (int it = 0; it < 2; ++it) {
        int f = it * 256 + t;
        int row = f >> 5, ch = f & 31;
        int grow = base + row; if (grow > N - 1) grow = N - 1;
        const unsigned short* gp = (ch < 16)
            ? xb + (size_t)grow * 128 + ch * 8
            : Mm + (size_t)grow * 128 + (ch - 16) * 8;
        uint4 val = *(const uint4*)gp;
        *(uint4*)(As + row * GAST + ch * 8) = val;
    }
    __syncthreads();

    const unsigned msk = smask[c];
    const int g0 = 2 * wv, g1 = 2 * wv + 1;
    const bf16x8* VB = (const bf16x8*)Vp;

    f32x4 acc0 = (f32x4){0.f, 0.f, 0.f, 0.f};
    f32x4 acc1 = (f32x4){0.f, 0.f, 0.f, 0.f};
    bf16x8 b0 = VB[(g0 * 12) * 64 + lane];
    bf16x8 b1 = VB[(g1 * 12) * 64 + lane];
#pragma unroll
    for (int s2 = 0; s2 < 12; ++s2) {
        int sn = (s2 + 1 < 12) ? s2 + 1 : 0;        // branchless prefetch
        bf16x8 n0 = VB[(g0 * 12 + sn) * 64 + lane];
        bf16x8 n1 = VB[(g1 * 12 + sn) * 64 + lane];
        int seg = s2 >> 2, kk = (s2 & 3) * 32;
        bf16x8 a0 = *(const bf16x8*)(As + c * GAST + (seg == 1 ? 128 : 0) + kk + quad * 8);
        if (seg == 2) {                              // mask.x segment: AND with deg mask
            uint4 ai = __builtin_bit_cast(uint4, a0);
            ai.x &= msk; ai.y &= msk; ai.z &= msk; ai.w &= msk;
            a0 = __builtin_bit_cast(bf16x8, ai);
        }
        acc0 = __builtin_amdgcn_mfma_f32_16x16x32_bf16(a0, b0, acc0, 0, 0, 0);
        acc1 = __builtin_amdgcn_mfma_f32_16x16x32_bf16(a0, b1, acc1, 0, 0, 0);
        b0 = n0; b1 = n1;
    }

    // epilogue: + bias, ELU (fast exp), store. C/D: col=lane&15, row=quad*4+reg
    const int col0 = g0 * 16 + c, col1 = g1 * 16 + c;
    const float bv0 = bias[col0], bv1 = bias[col1];
#pragma unroll
    for (int reg = 0; reg < 4; ++reg) {
        int grow = base + quad * 4 + reg;
        if (grow < N) {
            float v0 = acc0[reg] + bv0;
            float v1 = acc1[reg] + bv1;
            out[(size_t)grow * 128 + col0] = (v0 > 0.f) ? v0 : __expf(v0) - 1.0f;
            out[(size_t)grow * 128 + col1] = (v1 > 0.f) ? v1 : __expf(v1) - 1.0f;
        }
    }
}

extern "C" void kernel_launch(void* const* d_in, const int* in_sizes, int n_in,
                              void* d_out, int out_size, void* d_ws, size_t ws_size,
                              hipStream_t stream) {
    const float* x  = (const float*)d_in[0];
    const float* Wg = (const float*)d_in[1];
    const float* Wl = (const float*)d_in[2];
    const float* Ws = (const float*)d_in[3];
    const float* b  = (const float*)d_in[4];
    const int*   src = (const int*)d_in[5];
    const int*   dst = (const int*)d_in[6];
    const int*   deg = (const int*)d_in[7];
    const int E = in_sizes[5];
    const int N = in_sizes[7];
    float* out = (float*)d_out;

    const size_t NB = (size_t)N * 128 * 2;                       // 12.8 MB
    unsigned short* Vp     = (unsigned short*)d_ws;              // 96 KB (packed B)
    int*            blkoff = (int*)((char*)d_ws + 98304);        // 32 KB reserved
    unsigned short* xb     = (unsigned short*)((char*)d_ws + 131072);
    unsigned short* Mm     = (unsigned short*)((char*)d_ws + 131072 + NB);

    const int nblk_g = (N + GNPB - 1) / GNPB;      // 6250
    const int noffb  = (nblk_g + 255) / 256;       // 25
    const int total8 = N * 16;
    const int nconv  = (total8 + 255) / 256;       // 3125

    prep<<<dim3(VP_BLOCKS + noffb + nconv), dim3(256), 0, stream>>>(
        x, Wg, Wl, Ws, dst, Vp, xb, blkoff, total8, nblk_g, noffb, E);
    gather<<<dim3(nblk_g), dim3(512), 0, stream>>>(xb, src, deg, blkoff, Mm, N);
    gemm<<<dim3((N + MNPB - 1) / MNPB), dim3(256), 0, stream>>>(xb, Mm, deg, Vp, b, out, N);
}